// Round 9
// baseline (148.108 us; speedup 1.0000x reference)
//
#include <hip/hip_runtime.h>

// ---------------------------------------------------------------------------
// CausalAttention: out = softmax(mask(QK^T/sqrt(D))) @ V,  Q/K/V = x @ W_{q,k,v}
// B=4, S=2048, D_IN=D_OUT=1024, fp32 in/out, bf16 MFMA internally.
// R9: scores moved to the 128^2 2-phase-dbuf core (R8's Vt kernel) with
// triangular block decode — in scores all live blocks have identical K=1024
// work, so the uniform-work argument for 128x64 tiles never applied; the
// fatter tile halves staging per FLOP and the counted vmcnt(8) dbuf hides
// HBM latency at 2 blocks/CU.
// ---------------------------------------------------------------------------

typedef __bf16 bf16x8 __attribute__((ext_vector_type(8)));
typedef float f32x4 __attribute__((ext_vector_type(4)));

__device__ __forceinline__ unsigned short f2bf(float f) {
  unsigned int u = __builtin_bit_cast(unsigned int, f);
  u += 0x7FFFu + ((u >> 16) & 1u);  // RNE
  return (unsigned short)(u >> 16);
}
__device__ __forceinline__ float bf2f(unsigned short h) {
  unsigned int u = ((unsigned int)h) << 16;
  return __builtin_bit_cast(float, u);
}

#define GLDS16(g, l)                                                                   \
  __builtin_amdgcn_global_load_lds((const __attribute__((address_space(1))) void*)(g), \
                                   (__attribute__((address_space(3))) void*)(l), 16, 0, 0)

// ---------------- merged: fp32->bf16 convert + W transpose ------------------
__global__ __launch_bounds__(256) void k_prep(const float* __restrict__ x,
                                              unsigned short* __restrict__ xb,
                                              const float* __restrict__ W0,
                                              const float* __restrict__ W1,
                                              const float* __restrict__ W2,
                                              unsigned short* __restrict__ Wt, long n, int ncvt,
                                              int D) {
  const int b = blockIdx.x;
  const int t = threadIdx.x;
  if (b < ncvt) {
    long i = ((long)b * 256 + t) * 8;
    if (i >= n) return;
    float4 a = *(const float4*)(x + i);
    float4 c = *(const float4*)(x + i + 4);
    uint4 o;
    o.x = (unsigned)f2bf(a.x) | ((unsigned)f2bf(a.y) << 16);
    o.y = (unsigned)f2bf(a.z) | ((unsigned)f2bf(a.w) << 16);
    o.z = (unsigned)f2bf(c.x) | ((unsigned)f2bf(c.y) << 16);
    o.w = (unsigned)f2bf(c.z) | ((unsigned)f2bf(c.w) << 16);
    *(uint4*)(xb + i) = o;
    return;
  }
  const int id = b - ncvt;
  const int nt = (D / 32) * (D / 32);
  const int z = id / nt;
  const int rem = id - z * nt;
  const int by = (rem >> 5) * 32, bx = (rem & 31) * 32;
  const float* W = z == 0 ? W0 : (z == 1 ? W1 : W2);
  unsigned short* out = Wt + (long)z * D * D;
  __shared__ float tile[32][33];
  const int tx = t & 31, ty = t >> 5;
#pragma unroll
  for (int j = 0; j < 4; ++j) tile[ty + j * 8][tx] = W[(long)(by + ty + j * 8) * D + bx + tx];
  __syncthreads();
#pragma unroll
  for (int j = 0; j < 4; ++j)
    out[(long)(bx + ty + j * 8) * D + by + tx] = f2bf(tile[tx][ty + j * 8]);
}

// ======================= 256^2 8-phase BT GEMM (projections) ================
template <typename CT>
__global__ __launch_bounds__(512, 2) void k_gemm256(const unsigned short* __restrict__ A,
                                                    const unsigned short* __restrict__ B,
                                                    CT* __restrict__ C, int nx, int ny, int N,
                                                    int K, long sA, long sB, long sC,
                                                    float alpha) {
  const unsigned bid = blockIdx.x;
  const unsigned cpx = gridDim.x >> 3;
  const unsigned logical = (bid & 7) * cpx + (bid >> 3);
  const int per_z = nx * ny;
  const int z = (int)(logical / per_z);
  const int rem = (int)(logical - (unsigned)z * per_z);
  const int by = rem / nx;
  const int bx = rem - by * nx;
  const int m0 = by * 256, n0 = bx * 256;
  A += (long)z * sA;
  B += (long)z * sB;
  C += (long)z * sC;

  __shared__ char lds[131072];

  const int t = threadIdx.x;
  const int l = t & 63;
  const int w = t >> 6;
  const int wm = w >> 2;
  const int wn = w & 3;

  const int srow = t >> 3;
  const int sch = (t & 7) ^ (srow & 7);
  const int soff = t * 16;

#define STG(mat, bf, hf, kt)                                                              \
  do {                                                                                    \
    const unsigned short* g =                                                             \
        ((mat) ? B + (long)(n0 + (hf)*128 + srow) * K : A + (long)(m0 + (hf)*128 + srow) * K) + \
        (long)(kt)*64 + sch * 8;                                                          \
    char* d = lds + (mat)*65536 + (bf)*32768 + (hf)*16384 + soff;                         \
    GLDS16(g, d);                                                                         \
    GLDS16(g + (long)64 * K, d + 8192);                                                   \
  } while (0)

  const int lx = l & 15;
  const int kx0 = ((l >> 4) ^ (l & 7)) * 16;
  const int kx1 = ((4 + (l >> 4)) ^ (l & 7)) * 16;
  char* const aB = lds + wm * 16384 + lx * 128;
  char* const bB = lds + 65536 + (wn >> 1) * 16384 + ((wn & 1) * 64 + lx) * 128;

  bf16x8 av[4][2], bv0[2][2], bv1[2][2];
  f32x4 acc[8][4];
#pragma unroll
  for (int i = 0; i < 8; ++i)
#pragma unroll
    for (int jn = 0; jn < 4; ++jn) acc[i][jn] = f32x4{0.f, 0.f, 0.f, 0.f};

#define RDA(bf, mh)                                                     \
  do {                                                                  \
    _Pragma("unroll") for (int m4 = 0; m4 < 4; ++m4) {                  \
      char* p = aB + (bf)*32768 + ((mh)*64 + m4 * 16) * 128;            \
      av[m4][0] = *(const bf16x8*)(p + kx0);                            \
      av[m4][1] = *(const bf16x8*)(p + kx1);                            \
    }                                                                   \
  } while (0)
#define RDB(dst, bf, nh)                                                \
  do {                                                                  \
    _Pragma("unroll") for (int n2 = 0; n2 < 2; ++n2) {                  \
      char* p = bB + (bf)*32768 + (((nh)*2 + n2) * 16) * 128;           \
      dst[n2][0] = *(const bf16x8*)(p + kx0);                           \
      dst[n2][1] = *(const bf16x8*)(p + kx1);                           \
    }                                                                   \
  } while (0)
#define MFM(bv, mh, nh)                                                                    \
  do {                                                                                     \
    __builtin_amdgcn_s_setprio(1);                                                         \
    _Pragma("unroll") for (int m4 = 0; m4 < 4; ++m4) _Pragma("unroll") for (int n2 = 0;    \
                                                                            n2 < 2; ++n2) { \
      acc[(mh)*4 + m4][(nh)*2 + n2] = __builtin_amdgcn_mfma_f32_16x16x32_bf16(             \
          av[m4][0], bv[n2][0], acc[(mh)*4 + m4][(nh)*2 + n2], 0, 0, 0);                   \
      acc[(mh)*4 + m4][(nh)*2 + n2] = __builtin_amdgcn_mfma_f32_16x16x32_bf16(             \
          av[m4][1], bv[n2][1], acc[(mh)*4 + m4][(nh)*2 + n2], 0, 0, 0);                   \
    }                                                                                      \
    __builtin_amdgcn_s_setprio(0);                                                         \
  } while (0)
#define BAR __builtin_amdgcn_s_barrier()
#define VMC(n) asm volatile("s_waitcnt vmcnt(" #n ")" ::: "memory")

  const int KT = K >> 6;
  const int NIT = KT >> 1;

  STG(0, 0, 0, 0); STG(0, 0, 1, 0); STG(1, 0, 0, 0); STG(1, 0, 1, 0);
  STG(1, 1, 0, 1); STG(1, 1, 1, 1); STG(0, 1, 0, 1);
  VMC(6);
  BAR;

  for (int j = 0; j < NIT; ++j) {
    const bool full = (j < NIT - 1);
    RDA(0, 0); RDB(bv0, 0, 0);
    STG(0, 1, 1, 2 * j + 1);
    BAR; MFM(bv0, 0, 0); BAR;
    RDB(bv1, 0, 1);
    BAR; MFM(bv1, 0, 1); BAR;
    RDA(0, 1);
    if (full) STG(1, 0, 0, 2 * j + 2);
    BAR; MFM(bv1, 1, 1); BAR;
    if (full) {
      STG(0, 0, 0, 2 * j + 2); STG(1, 0, 1, 2 * j + 2);
      VMC(6);
    } else {
      VMC(0);
    }
    BAR; MFM(bv0, 1, 0); BAR;
    RDA(1, 0); RDB(bv0, 1, 0);
    if (full) STG(0, 0, 1, 2 * j + 2);
    BAR; MFM(bv0, 0, 0); BAR;
    RDB(bv1, 1, 1);
    BAR; MFM(bv1, 0, 1); BAR;
    RDA(1, 1);
    if (full) STG(1, 1, 0, 2 * j + 3);
    BAR; MFM(bv1, 1, 1); BAR;
    if (full) {
      STG(1, 1, 1, 2 * j + 3); STG(0, 1, 0, 2 * j + 3);
      VMC(6);
    }
    BAR; MFM(bv0, 1, 0); BAR;
  }

  const int rb = m0 + wm * 128 + (l >> 4) * 4;
  const int cb = n0 + wn * 64 + (l & 15);
#pragma unroll
  for (int m = 0; m < 8; ++m)
#pragma unroll
    for (int n = 0; n < 4; ++n)
#pragma unroll
      for (int i = 0; i < 4; ++i) {
        float v = acc[m][n][i] * alpha;
        long off = (long)(rb + m * 16 + i) * N + (cb + n * 16);
        if constexpr (sizeof(CT) == 2)
          C[off] = f2bf(v);
        else
          C[off] = v;
      }
#undef STG
#undef RDA
#undef RDB
#undef MFM
#undef BAR
#undef VMC
}

// ========== 128^2 BT GEMM, 2-phase dbuf + vmcnt(8) (V^T and scores) =========
// TRI=0: dense row-major decode (Vt). TRI=1: triangular decode, live causal
// blocks only (scores; per_z = ny*(ny+1)/2 = 136, every block full K).
template <typename CT, int TRI>
__global__ __launch_bounds__(256) void k_gemm_bt(const unsigned short* __restrict__ A,
                                                 const unsigned short* __restrict__ B,
                                                 CT* __restrict__ C, int nx, int ny, int N, int K,
                                                 long sA, long sB, long sC, float alpha) {
  const unsigned bid = blockIdx.x;
  const unsigned cpx = gridDim.x >> 3;
  const unsigned logical = (bid & 7) * cpx + (bid >> 3);
  int z, by, bx;
  if constexpr (TRI) {
    const int per_z = ny * (ny + 1) / 2;
    z = (int)(logical / per_z);
    int r = (int)(logical - (unsigned)z * per_z);
    int b = (int)((sqrtf(8.f * (float)r + 1.f) - 1.f) * 0.5f);
    while ((b + 1) * (b + 2) / 2 <= r) ++b;
    while (b * (b + 1) / 2 > r) --b;
    by = b;
    bx = r - b * (b + 1) / 2;
  } else {
    const int per_z = nx * ny;
    z = (int)(logical / per_z);
    int r = (int)(logical - (unsigned)z * per_z);
    by = r / nx;
    bx = r - by * nx;
  }
  const int m0 = by * 128;
  const int n0 = bx * 128;
  A += (long)z * sA;
  B += (long)z * sB;
  C += (long)z * sC;

  __shared__ unsigned short As[2 * 128 * 64];
  __shared__ unsigned short Bs[2 * 128 * 64];
  char* const AsB = (char*)As;
  char* const BsB = (char*)Bs;

  const int t = threadIdx.x;
  const int l = t & 63;
  const int w = t >> 6;
  const int wr = (w >> 1) * 64;
  const int wc = (w & 1) * 64;

  const int srow = t >> 3;
  const int sch = (t & 7) ^ (srow & 7);
  const unsigned short* Ag = A + (long)(m0 + srow) * K + sch * 8;
  const unsigned short* Bg = B + (long)(n0 + srow) * K + sch * 8;
  const int soff = t * 16;

  const int ar = wr + (l & 15);
  const int brr = wc + (l & 15);
  const int kc = l >> 4;

  f32x4 acc[4][4];
#pragma unroll
  for (int i = 0; i < 4; ++i)
#pragma unroll
    for (int j = 0; j < 4; ++j) acc[i][j] = f32x4{0.f, 0.f, 0.f, 0.f};

#define STGBT(kt, bf)                                                                     \
  do {                                                                                    \
    const long ko = (long)(kt)*64;                                                        \
    _Pragma("unroll") for (int i = 0; i < 4; ++i)                                         \
        GLDS16(Ag + (long)i * 32 * K + ko, AsB + (bf)*16384 + i * 4096 + soff);           \
    _Pragma("unroll") for (int i = 0; i < 4; ++i)                                         \
        GLDS16(Bg + (long)i * 32 * K + ko, BsB + (bf)*16384 + i * 4096 + soff);           \
  } while (0)

  const int KT = K >> 6;
  STGBT(0, 0);
  for (int kt = 0; kt < KT; ++kt) {
    if (kt + 1 < KT) {
      STGBT(kt + 1, (kt + 1) & 1);
      asm volatile("s_waitcnt vmcnt(8)" ::: "memory");
    } else {
      asm volatile("s_waitcnt vmcnt(0)" ::: "memory");
    }
    __builtin_amdgcn_s_barrier();
    const int bf = kt & 1;
#pragma unroll
    for (int kk = 0; kk < 2; ++kk) {
      bf16x8 av[4], bv[4];
#pragma unroll
      for (int m = 0; m < 4; ++m) {
        int rr = ar + m * 16;
        int c = (kk * 4 + kc) ^ (rr & 7);
        av[m] = *(const bf16x8*)(AsB + bf * 16384 + rr * 128 + c * 16);
      }
#pragma unroll
      for (int n = 0; n < 4; ++n) {
        int rr = brr + n * 16;
        int c = (kk * 4 + kc) ^ (rr & 7);
        bv[n] = *(const bf16x8*)(BsB + bf * 16384 + rr * 128 + c * 16);
      }
#pragma unroll
      for (int m = 0; m < 4; ++m)
#pragma unroll
        for (int n = 0; n < 4; ++n)
          acc[m][n] = __builtin_amdgcn_mfma_f32_16x16x32_bf16(av[m], bv[n], acc[m][n], 0, 0, 0);
    }
    __builtin_amdgcn_s_barrier();
  }
#undef STGBT

  const int rb = m0 + wr + (l >> 4) * 4;
  const int cb = n0 + wc + (l & 15);
#pragma unroll
  for (int m = 0; m < 4; ++m)
#pragma unroll
    for (int n = 0; n < 4; ++n)
#pragma unroll
      for (int i = 0; i < 4; ++i) {
        float v = acc[m][n][i] * alpha;
        long off = (long)(rb + m * 16 + i) * N + (cb + n * 16);
        if constexpr (sizeof(CT) == 2)
          C[off] = f2bf(v);
        else
          C[off] = v;
      }
}

// ======================= 128x64 BT GEMM (PV only) ===========================
// Fused row-pair (by, 15-by), 34 K-tiles/block uniform; 3-buffer depth-2
// pipeline, vmcnt(12)/(6)/(0); K clamped at the causal diagonal per segment.
template <typename CT>
__global__ __launch_bounds__(256) void k_gemm_pv(const unsigned short* __restrict__ A,
                                                 const unsigned short* __restrict__ B,
                                                 CT* __restrict__ C, int N, int K, long sA,
                                                 long sB, long sC, float alpha) {
  const unsigned bid = blockIdx.x;
  const unsigned cpx = gridDim.x >> 3;
  const unsigned logical = (bid & 7) * cpx + (bid >> 3);
  const int nx = N >> 6;
  const int per_z = 8 * nx;
  const int z = (int)(logical / per_z);
  int r = (int)(logical - (unsigned)z * per_z);
  const int by = r / nx;
  const int bx = r - by * nx;
  A += (long)z * sA;
  B += (long)z * sB;
  C += (long)z * sC;

  __shared__ unsigned short As[3 * 128 * 64];
  __shared__ unsigned short Bs[3 * 64 * 64];
  char* const AsB = (char*)As;
  char* const BsB = (char*)Bs;

  const int t = threadIdx.x;
  const int l = t & 63;
  const int w = t >> 6;
  const int wr = (w >> 1) * 64;
  const int wc = (w & 1) * 32;

  const int srow = t >> 3;
  const int sch = (t & 7) ^ (srow & 7);
  const int soff = t * 16;

  const int ar = wr + (l & 15);
  const int brr = wc + (l & 15);
  const int kc = l >> 4;

  const int n0 = bx * 64;
  const unsigned short* Bg = B + (long)(n0 + srow) * K + sch * 8;

#define STG64(Agp, kt, bf)                                                           \
  do {                                                                               \
    const long ko = (long)(kt)*64;                                                   \
    _Pragma("unroll") for (int i = 0; i < 4; ++i)                                    \
        GLDS16((Agp) + (long)i * 32 * K + ko, AsB + (bf)*16384 + i * 4096 + soff);   \
    _Pragma("unroll") for (int i = 0; i < 2; ++i)                                    \
        GLDS16(Bg + (long)i * 32 * K + ko, BsB + (bf)*8192 + i * 4096 + soff);       \
  } while (0)

#define CMP64(bf)                                                                    \
  do {                                                                               \
    _Pragma("unroll") for (int kk = 0; kk < 2; ++kk) {                               \
      bf16x8 av[4], bv[2];                                                           \
      _Pragma("unroll") for (int m = 0; m < 4; ++m) {                                \
        int rr = ar + m * 16;                                                        \
        int c = (kk * 4 + kc) ^ (rr & 7);                                            \
        av[m] = *(const bf16x8*)(AsB + (bf)*16384 + rr * 128 + c * 16);              \
      }                                                                              \
      _Pragma("unroll") for (int n = 0; n < 2; ++n) {                                \
        int rr = brr + n * 16;                                                       \
        int c = (kk * 4 + kc) ^ (rr & 7);                                            \
        bv[n] = *(const bf16x8*)(BsB + (bf)*8192 + rr * 128 + c * 16);               \
      }                                                                              \
      _Pragma("unroll") for (int m = 0; m < 4; ++m) _Pragma("unroll") for (int n = 0; \
                                                                          n < 2; ++n) \
          acc[m][n] = __builtin_amdgcn_mfma_f32_16x16x32_bf16(av[m], bv[n], acc[m][n], 0, 0, 0); \
    }                                                                                \
  } while (0)

  for (int seg = 0; seg < 2; ++seg) {
    const int row = seg ? (15 - by) : by;
    const int m0 = row * 128;
    const int KT = (m0 + 128) >> 6;
    const unsigned short* Ag = A + (long)(m0 + srow) * K + sch * 8;

    f32x4 acc[4][2];
#pragma unroll
    for (int i = 0; i < 4; ++i)
#pragma unroll
      for (int j = 0; j < 2; ++j) acc[i][j] = f32x4{0.f, 0.f, 0.f, 0.f};

    STG64(Ag, 0, 0);
    STG64(Ag, 1, 1);  // KT >= 2 always
    for (int kt = 0; kt < KT; ++kt) {
      if (kt + 2 < KT) {
        STG64(Ag, kt + 2, (kt + 2) % 3);
        asm volatile("s_waitcnt vmcnt(12)" ::: "memory");
      } else if (kt + 1 < KT) {
        asm volatile("s_waitcnt vmcnt(6)" ::: "memory");
      } else {
        asm volatile("s_waitcnt vmcnt(0)" ::: "memory");
      }
      __builtin_amdgcn_s_barrier();
      CMP64(kt % 3);
      __builtin_amdgcn_s_barrier();
    }

    const int rb = m0 + wr + (l >> 4) * 4;
    const int cb = n0 + wc + (l & 15);
#pragma unroll
    for (int m = 0; m < 4; ++m)
#pragma unroll
      for (int n = 0; n < 2; ++n)
#pragma unroll
        for (int i = 0; i < 4; ++i) {
          float v = acc[m][n][i] * alpha;
          long off = (long)(rb + m * 16 + i) * N + (cb + n * 16);
          if constexpr (sizeof(CT) == 2)
            C[off] = f2bf(v);
          else
            C[off] = v;
        }
  }
#undef STG64
#undef CMP64
}

// ---------------- causal row softmax, live-region only ----------------------
__global__ __launch_bounds__(256) void k_softmax(unsigned short* __restrict__ P, int S) {
  const int t = threadIdx.x;
  const int wv = t >> 6, l = t & 63;
  const int q = blockIdx.x * 4 + wv;
  unsigned short* row = P + ((long)blockIdx.y * S + q) * S;
  const int nch = (q >> 9) + 1;

  uint4 raw[4];
  float v[32];
#pragma unroll
  for (int j = 0; j < 4; ++j)
    if (j < nch) raw[j] = ((const uint4*)row)[j * 64 + l];
#pragma unroll
  for (int j = 0; j < 4; ++j) {
    if (j < nch) {
      unsigned int rw[4] = {raw[j].x, raw[j].y, raw[j].z, raw[j].w};
#pragma unroll
      for (int e = 0; e < 8; ++e)
        v[j * 8 + e] = bf2f((unsigned short)((rw[e >> 1] >> ((e & 1) * 16)) & 0xFFFF));
    }
  }

  float mx = -3.0e38f;
#pragma unroll
  for (int j = 0; j < 4; ++j)
    if (j < nch) {
#pragma unroll
      for (int e = 0; e < 8; ++e) {
        int col = j * 512 + l * 8 + e;
        if (col <= q) mx = fmaxf(mx, v[j * 8 + e]);
      }
    }
#pragma unroll
  for (int o = 32; o >= 1; o >>= 1) mx = fmaxf(mx, __shfl_xor(mx, o, 64));

  float s = 0.f;
#pragma unroll
  for (int j = 0; j < 4; ++j)
    if (j < nch) {
#pragma unroll
      for (int e = 0; e < 8; ++e) {
        int col = j * 512 + l * 8 + e;
        float ev = (col <= q) ? __expf(v[j * 8 + e] - mx) : 0.f;
        v[j * 8 + e] = ev;
        s += ev;
      }
    }
#pragma unroll
  for (int o = 32; o >= 1; o >>= 1) s += __shfl_xor(s, o, 64);
  const float inv = 1.f / s;

#pragma unroll
  for (int j = 0; j < 4; ++j)
    if (j < nch) {
      uint4 ow;
      unsigned int o2[4];
#pragma unroll
      for (int jj = 0; jj < 4; ++jj)
        o2[jj] = (unsigned)f2bf(v[j * 8 + 2 * jj] * inv) |
                 ((unsigned)f2bf(v[j * 8 + 2 * jj + 1] * inv) << 16);
      ow.x = o2[0]; ow.y = o2[1]; ow.z = o2[2]; ow.w = o2[3];
      ((uint4*)row)[j * 64 + l] = ow;
    }
}

// ---------------------------------------------------------------------------
extern "C" void kernel_launch(void* const* d_in, const int* in_sizes, int n_in, void* d_out,
                              int out_size, void* d_ws, size_t ws_size, hipStream_t stream) {
  const int B = 4, S = 2048, D = 1024;
  const long MS = (long)B * S;

  const float* x = (const float*)d_in[0];
  const float* Wq = (const float*)d_in[1];
  const float* Wk = (const float*)d_in[2];
  const float* Wv = (const float*)d_in[3];
  float* out = (float*)d_out;

  unsigned short* xb = (unsigned short*)d_ws;   // [8192][1024]
  unsigned short* Wt = xb + MS * D;             // 3 x [1024][1024] (transposed)
  unsigned short* Qb = Wt + 3L * D * D;         // [8192][1024]
  unsigned short* Kb = Qb + MS * D;             // [8192][1024]
  unsigned short* Vt = Kb + MS * D;             // 4 x [1024][2048]
  unsigned short* P  = Vt + MS * D;             // 4 x [2048][2048]
  (void)ws_size;

  long n = MS * D;
  const int ncvt = (int)(n / 8 / 256);
  const int ntrw = 3 * (D / 32) * (D / 32);
  k_prep<<<ncvt + ntrw, 256, 0, stream>>>(x, xb, Wq, Wk, Wv, Wt, n, ncvt, D);
  // Q,K projections (8-phase 256^2): nwg = 4*32*2 = 256
  k_gemm256<unsigned short><<<256, 512, 0, stream>>>(
      xb, Wt, Qb, /*nx=*/D / 256, /*ny=*/(int)(MS / 256), /*N=*/D, /*K=*/D,
      /*sA=*/0L, /*sB=*/(long)D * D, /*sC=*/MS * D, 1.0f);
  // V^T direct (2-phase dbuf): nwg = 16*8*4 = 512
  k_gemm_bt<unsigned short, 0><<<512, 256, 0, stream>>>(
      Wt + 2L * D * D, xb, Vt, /*nx=*/S / 128, /*ny=*/D / 128, /*N=*/S, /*K=*/D,
      /*sA=*/0L, /*sB=*/(long)S * D, /*sC=*/(long)D * S, 1.0f);
  // scores: 128^2 triangular + 2-phase dbuf (nwg = 4 * 136 = 544)
  k_gemm_bt<unsigned short, 1><<<544, 256, 0, stream>>>(
      Qb, Kb, P, /*nx=*/S / 128, /*ny=*/S / 128, /*N=*/S, /*K=*/D,
      /*sA=*/(long)S * D, /*sB=*/(long)S * D, /*sC=*/(long)S * S, 0.03125f);
  // causal softmax (live region only)
  k_softmax<<<dim3(S / 4, B), 256, 0, stream>>>(P, S);
  // PV: fused row-pairs, depth-2 pipeline (nwg = 4*8*16 = 512)
  k_gemm_pv<float><<<512, 256, 0, stream>>>(
      P, Vt, out, /*N=*/D, /*K=*/S,
      /*sA=*/(long)S * S, /*sB=*/(long)D * S, /*sC=*/(long)S * D, 1.0f);
}

// Round 10
// 142.090 us; speedup vs baseline: 1.0424x; 1.0424x over previous
//
#include <hip/hip_runtime.h>

// ---------------------------------------------------------------------------
// CausalAttention: out = softmax(mask(QK^T/sqrt(D))) @ V,  Q/K/V = x @ W_{q,k,v}
// B=4, S=2048, D_IN=D_OUT=1024, fp32 in/out, bf16 MFMA internally.
// R10: revert R9's scores-on-128^2 (64KB dbuf capped occupancy at 2/CU vs
// 2.125 demand -> 1.41x quantization stretch, +9us). Scores back to 128x64
// triangular 1088-block config (4.25/CU, stretch 1.18) + 2-buffer counted
// vmcnt(6) pipeline (48KB -> 3/CU cap, queue backfill keeps CUs busy).
// ---------------------------------------------------------------------------

typedef __bf16 bf16x8 __attribute__((ext_vector_type(8)));
typedef float f32x4 __attribute__((ext_vector_type(4)));

__device__ __forceinline__ unsigned short f2bf(float f) {
  unsigned int u = __builtin_bit_cast(unsigned int, f);
  u += 0x7FFFu + ((u >> 16) & 1u);  // RNE
  return (unsigned short)(u >> 16);
}
__device__ __forceinline__ float bf2f(unsigned short h) {
  unsigned int u = ((unsigned int)h) << 16;
  return __builtin_bit_cast(float, u);
}

#define GLDS16(g, l)                                                                   \
  __builtin_amdgcn_global_load_lds((const __attribute__((address_space(1))) void*)(g), \
                                   (__attribute__((address_space(3))) void*)(l), 16, 0, 0)

// ---------------- merged: fp32->bf16 convert + W transpose ------------------
__global__ __launch_bounds__(256) void k_prep(const float* __restrict__ x,
                                              unsigned short* __restrict__ xb,
                                              const float* __restrict__ W0,
                                              const float* __restrict__ W1,
                                              const float* __restrict__ W2,
                                              unsigned short* __restrict__ Wt, long n, int ncvt,
                                              int D) {
  const int b = blockIdx.x;
  const int t = threadIdx.x;
  if (b < ncvt) {
    long i = ((long)b * 256 + t) * 8;
    if (i >= n) return;
    float4 a = *(const float4*)(x + i);
    float4 c = *(const float4*)(x + i + 4);
    uint4 o;
    o.x = (unsigned)f2bf(a.x) | ((unsigned)f2bf(a.y) << 16);
    o.y = (unsigned)f2bf(a.z) | ((unsigned)f2bf(a.w) << 16);
    o.z = (unsigned)f2bf(c.x) | ((unsigned)f2bf(c.y) << 16);
    o.w = (unsigned)f2bf(c.z) | ((unsigned)f2bf(c.w) << 16);
    *(uint4*)(xb + i) = o;
    return;
  }
  const int id = b - ncvt;
  const int nt = (D / 32) * (D / 32);
  const int z = id / nt;
  const int rem = id - z * nt;
  const int by = (rem >> 5) * 32, bx = (rem & 31) * 32;
  const float* W = z == 0 ? W0 : (z == 1 ? W1 : W2);
  unsigned short* out = Wt + (long)z * D * D;
  __shared__ float tile[32][33];
  const int tx = t & 31, ty = t >> 5;
#pragma unroll
  for (int j = 0; j < 4; ++j) tile[ty + j * 8][tx] = W[(long)(by + ty + j * 8) * D + bx + tx];
  __syncthreads();
#pragma unroll
  for (int j = 0; j < 4; ++j)
    out[(long)(bx + ty + j * 8) * D + by + tx] = f2bf(tile[tx][ty + j * 8]);
}

// ======================= 256^2 8-phase BT GEMM (projections) ================
template <typename CT>
__global__ __launch_bounds__(512, 2) void k_gemm256(const unsigned short* __restrict__ A,
                                                    const unsigned short* __restrict__ B,
                                                    CT* __restrict__ C, int nx, int ny, int N,
                                                    int K, long sA, long sB, long sC,
                                                    float alpha) {
  const unsigned bid = blockIdx.x;
  const unsigned cpx = gridDim.x >> 3;
  const unsigned logical = (bid & 7) * cpx + (bid >> 3);
  const int per_z = nx * ny;
  const int z = (int)(logical / per_z);
  const int rem = (int)(logical - (unsigned)z * per_z);
  const int by = rem / nx;
  const int bx = rem - by * nx;
  const int m0 = by * 256, n0 = bx * 256;
  A += (long)z * sA;
  B += (long)z * sB;
  C += (long)z * sC;

  __shared__ char lds[131072];

  const int t = threadIdx.x;
  const int l = t & 63;
  const int w = t >> 6;
  const int wm = w >> 2;
  const int wn = w & 3;

  const int srow = t >> 3;
  const int sch = (t & 7) ^ (srow & 7);
  const int soff = t * 16;

#define STG(mat, bf, hf, kt)                                                              \
  do {                                                                                    \
    const unsigned short* g =                                                             \
        ((mat) ? B + (long)(n0 + (hf)*128 + srow) * K : A + (long)(m0 + (hf)*128 + srow) * K) + \
        (long)(kt)*64 + sch * 8;                                                          \
    char* d = lds + (mat)*65536 + (bf)*32768 + (hf)*16384 + soff;                         \
    GLDS16(g, d);                                                                         \
    GLDS16(g + (long)64 * K, d + 8192);                                                   \
  } while (0)

  const int lx = l & 15;
  const int kx0 = ((l >> 4) ^ (l & 7)) * 16;
  const int kx1 = ((4 + (l >> 4)) ^ (l & 7)) * 16;
  char* const aB = lds + wm * 16384 + lx * 128;
  char* const bB = lds + 65536 + (wn >> 1) * 16384 + ((wn & 1) * 64 + lx) * 128;

  bf16x8 av[4][2], bv0[2][2], bv1[2][2];
  f32x4 acc[8][4];
#pragma unroll
  for (int i = 0; i < 8; ++i)
#pragma unroll
    for (int jn = 0; jn < 4; ++jn) acc[i][jn] = f32x4{0.f, 0.f, 0.f, 0.f};

#define RDA(bf, mh)                                                     \
  do {                                                                  \
    _Pragma("unroll") for (int m4 = 0; m4 < 4; ++m4) {                  \
      char* p = aB + (bf)*32768 + ((mh)*64 + m4 * 16) * 128;            \
      av[m4][0] = *(const bf16x8*)(p + kx0);                            \
      av[m4][1] = *(const bf16x8*)(p + kx1);                            \
    }                                                                   \
  } while (0)
#define RDB(dst, bf, nh)                                                \
  do {                                                                  \
    _Pragma("unroll") for (int n2 = 0; n2 < 2; ++n2) {                  \
      char* p = bB + (bf)*32768 + (((nh)*2 + n2) * 16) * 128;           \
      dst[n2][0] = *(const bf16x8*)(p + kx0);                           \
      dst[n2][1] = *(const bf16x8*)(p + kx1);                           \
    }                                                                   \
  } while (0)
#define MFM(bv, mh, nh)                                                                    \
  do {                                                                                     \
    __builtin_amdgcn_s_setprio(1);                                                         \
    _Pragma("unroll") for (int m4 = 0; m4 < 4; ++m4) _Pragma("unroll") for (int n2 = 0;    \
                                                                            n2 < 2; ++n2) { \
      acc[(mh)*4 + m4][(nh)*2 + n2] = __builtin_amdgcn_mfma_f32_16x16x32_bf16(             \
          av[m4][0], bv[n2][0], acc[(mh)*4 + m4][(nh)*2 + n2], 0, 0, 0);                   \
      acc[(mh)*4 + m4][(nh)*2 + n2] = __builtin_amdgcn_mfma_f32_16x16x32_bf16(             \
          av[m4][1], bv[n2][1], acc[(mh)*4 + m4][(nh)*2 + n2], 0, 0, 0);                   \
    }                                                                                      \
    __builtin_amdgcn_s_setprio(0);                                                         \
  } while (0)
#define BAR __builtin_amdgcn_s_barrier()
#define VMC(n) asm volatile("s_waitcnt vmcnt(" #n ")" ::: "memory")

  const int KT = K >> 6;
  const int NIT = KT >> 1;

  STG(0, 0, 0, 0); STG(0, 0, 1, 0); STG(1, 0, 0, 0); STG(1, 0, 1, 0);
  STG(1, 1, 0, 1); STG(1, 1, 1, 1); STG(0, 1, 0, 1);
  VMC(6);
  BAR;

  for (int j = 0; j < NIT; ++j) {
    const bool full = (j < NIT - 1);
    RDA(0, 0); RDB(bv0, 0, 0);
    STG(0, 1, 1, 2 * j + 1);
    BAR; MFM(bv0, 0, 0); BAR;
    RDB(bv1, 0, 1);
    BAR; MFM(bv1, 0, 1); BAR;
    RDA(0, 1);
    if (full) STG(1, 0, 0, 2 * j + 2);
    BAR; MFM(bv1, 1, 1); BAR;
    if (full) {
      STG(0, 0, 0, 2 * j + 2); STG(1, 0, 1, 2 * j + 2);
      VMC(6);
    } else {
      VMC(0);
    }
    BAR; MFM(bv0, 1, 0); BAR;
    RDA(1, 0); RDB(bv0, 1, 0);
    if (full) STG(0, 0, 1, 2 * j + 2);
    BAR; MFM(bv0, 0, 0); BAR;
    RDB(bv1, 1, 1);
    BAR; MFM(bv1, 0, 1); BAR;
    RDA(1, 1);
    if (full) STG(1, 1, 0, 2 * j + 3);
    BAR; MFM(bv1, 1, 1); BAR;
    if (full) {
      STG(1, 1, 1, 2 * j + 3); STG(0, 1, 0, 2 * j + 3);
      VMC(6);
    }
    BAR; MFM(bv0, 1, 0); BAR;
  }

  const int rb = m0 + wm * 128 + (l >> 4) * 4;
  const int cb = n0 + wn * 64 + (l & 15);
#pragma unroll
  for (int m = 0; m < 8; ++m)
#pragma unroll
    for (int n = 0; n < 4; ++n)
#pragma unroll
      for (int i = 0; i < 4; ++i) {
        float v = acc[m][n][i] * alpha;
        long off = (long)(rb + m * 16 + i) * N + (cb + n * 16);
        if constexpr (sizeof(CT) == 2)
          C[off] = f2bf(v);
        else
          C[off] = v;
      }
#undef STG
#undef RDA
#undef RDB
#undef MFM
#undef BAR
#undef VMC
}

// ============== 128^2 BT GEMM, 2-phase dbuf + vmcnt(8) (V^T) ================
template <typename CT>
__global__ __launch_bounds__(256) void k_gemm_bt(const unsigned short* __restrict__ A,
                                                 const unsigned short* __restrict__ B,
                                                 CT* __restrict__ C, int nx, int ny, int N, int K,
                                                 long sA, long sB, long sC, float alpha) {
  const unsigned bid = blockIdx.x;
  const unsigned cpx = gridDim.x >> 3;
  const unsigned logical = (bid & 7) * cpx + (bid >> 3);
  const int per_z = nx * ny;
  const int z = (int)(logical / per_z);
  const int r = (int)(logical - (unsigned)z * per_z);
  const int by = r / nx;
  const int bx = r - by * nx;
  const int m0 = by * 128;
  const int n0 = bx * 128;
  A += (long)z * sA;
  B += (long)z * sB;
  C += (long)z * sC;

  __shared__ unsigned short As[2 * 128 * 64];
  __shared__ unsigned short Bs[2 * 128 * 64];
  char* const AsB = (char*)As;
  char* const BsB = (char*)Bs;

  const int t = threadIdx.x;
  const int l = t & 63;
  const int w = t >> 6;
  const int wr = (w >> 1) * 64;
  const int wc = (w & 1) * 64;

  const int srow = t >> 3;
  const int sch = (t & 7) ^ (srow & 7);
  const unsigned short* Ag = A + (long)(m0 + srow) * K + sch * 8;
  const unsigned short* Bg = B + (long)(n0 + srow) * K + sch * 8;
  const int soff = t * 16;

  const int ar = wr + (l & 15);
  const int brr = wc + (l & 15);
  const int kc = l >> 4;

  f32x4 acc[4][4];
#pragma unroll
  for (int i = 0; i < 4; ++i)
#pragma unroll
    for (int j = 0; j < 4; ++j) acc[i][j] = f32x4{0.f, 0.f, 0.f, 0.f};

#define STGBT(kt, bf)                                                                     \
  do {                                                                                    \
    const long ko = (long)(kt)*64;                                                        \
    _Pragma("unroll") for (int i = 0; i < 4; ++i)                                         \
        GLDS16(Ag + (long)i * 32 * K + ko, AsB + (bf)*16384 + i * 4096 + soff);           \
    _Pragma("unroll") for (int i = 0; i < 4; ++i)                                         \
        GLDS16(Bg + (long)i * 32 * K + ko, BsB + (bf)*16384 + i * 4096 + soff);           \
  } while (0)

  const int KT = K >> 6;
  STGBT(0, 0);
  for (int kt = 0; kt < KT; ++kt) {
    if (kt + 1 < KT) {
      STGBT(kt + 1, (kt + 1) & 1);
      asm volatile("s_waitcnt vmcnt(8)" ::: "memory");
    } else {
      asm volatile("s_waitcnt vmcnt(0)" ::: "memory");
    }
    __builtin_amdgcn_s_barrier();
    const int bf = kt & 1;
#pragma unroll
    for (int kk = 0; kk < 2; ++kk) {
      bf16x8 av[4], bv[4];
#pragma unroll
      for (int m = 0; m < 4; ++m) {
        int rr = ar + m * 16;
        int c = (kk * 4 + kc) ^ (rr & 7);
        av[m] = *(const bf16x8*)(AsB + bf * 16384 + rr * 128 + c * 16);
      }
#pragma unroll
      for (int n = 0; n < 4; ++n) {
        int rr = brr + n * 16;
        int c = (kk * 4 + kc) ^ (rr & 7);
        bv[n] = *(const bf16x8*)(BsB + bf * 16384 + rr * 128 + c * 16);
      }
#pragma unroll
      for (int m = 0; m < 4; ++m)
#pragma unroll
        for (int n = 0; n < 4; ++n)
          acc[m][n] = __builtin_amdgcn_mfma_f32_16x16x32_bf16(av[m], bv[n], acc[m][n], 0, 0, 0);
    }
    __builtin_amdgcn_s_barrier();
  }
#undef STGBT

  const int rb = m0 + wr + (l >> 4) * 4;
  const int cb = n0 + wc + (l & 15);
#pragma unroll
  for (int m = 0; m < 4; ++m)
#pragma unroll
    for (int n = 0; n < 4; ++n)
#pragma unroll
      for (int i = 0; i < 4; ++i) {
        float v = acc[m][n][i] * alpha;
        long off = (long)(rb + m * 16 + i) * N + (cb + n * 16);
        if constexpr (sizeof(CT) == 2)
          C[off] = f2bf(v);
        else
          C[off] = v;
      }
}

// ======================= 128x64 BT GEMM, uniform-work modes =================
// MODE 0 (scores): 64-col triangular decode, 1088 uniform blocks; 2-buffer
//   counted vmcnt(6) pipeline (48 KiB -> 3 blocks/CU, queue backfill).
// MODE 1 (PV): fused row-pair (by, 15-by), 34 K-tiles/block uniform; 3-buffer
//   depth-2 pipeline, vmcnt(12)/(6)/(0); K clamped at causal diagonal.
template <typename CT, int MODE>
__global__ __launch_bounds__(256) void k_gemm_bt64(const unsigned short* __restrict__ A,
                                                   const unsigned short* __restrict__ B,
                                                   CT* __restrict__ C, int N, int K, long sA,
                                                   long sB, long sC, float alpha) {
  const unsigned bid = blockIdx.x;
  const unsigned cpx = gridDim.x >> 3;
  const unsigned logical = (bid & 7) * cpx + (bid >> 3);
  int z, by, bx;
  if constexpr (MODE == 0) {
    const int per_z = 272;
    z = (int)(logical / per_z);
    int r = (int)(logical - (unsigned)z * per_z);
    int b = (int)((sqrtf(4.f * (float)r + 1.f) - 1.f) * 0.5f);
    while ((b + 1) * (b + 2) <= r) ++b;
    while (b * (b + 1) > r) --b;
    by = b;
    bx = r - b * (b + 1);
  } else {
    const int nx = N >> 6;
    const int per_z = 8 * nx;
    z = (int)(logical / per_z);
    int r = (int)(logical - (unsigned)z * per_z);
    by = r / nx;
    bx = r - by * nx;
  }
  A += (long)z * sA;
  B += (long)z * sB;
  C += (long)z * sC;

  const int NB = (MODE == 1) ? 3 : 2;
  __shared__ unsigned short As[(MODE == 1 ? 3 : 2) * 128 * 64];
  __shared__ unsigned short Bs[(MODE == 1 ? 3 : 2) * 64 * 64];
  char* const AsB = (char*)As;
  char* const BsB = (char*)Bs;

  const int t = threadIdx.x;
  const int l = t & 63;
  const int w = t >> 6;
  const int wr = (w >> 1) * 64;
  const int wc = (w & 1) * 32;

  const int srow = t >> 3;
  const int sch = (t & 7) ^ (srow & 7);
  const int soff = t * 16;

  const int ar = wr + (l & 15);
  const int brr = wc + (l & 15);
  const int kc = l >> 4;

  const int n0 = bx * 64;
  const unsigned short* Bg = B + (long)(n0 + srow) * K + sch * 8;

#define STG64(Agp, kt, bf)                                                           \
  do {                                                                               \
    const long ko = (long)(kt)*64;                                                   \
    _Pragma("unroll") for (int i = 0; i < 4; ++i)                                    \
        GLDS16((Agp) + (long)i * 32 * K + ko, AsB + (bf)*16384 + i * 4096 + soff);   \
    _Pragma("unroll") for (int i = 0; i < 2; ++i)                                    \
        GLDS16(Bg + (long)i * 32 * K + ko, BsB + (bf)*8192 + i * 4096 + soff);       \
  } while (0)

#define CMP64(bf)                                                                    \
  do {                                                                               \
    _Pragma("unroll") for (int kk = 0; kk < 2; ++kk) {                               \
      bf16x8 av[4], bv[2];                                                           \
      _Pragma("unroll") for (int m = 0; m < 4; ++m) {                                \
        int rr = ar + m * 16;                                                        \
        int c = (kk * 4 + kc) ^ (rr & 7);                                            \
        av[m] = *(const bf16x8*)(AsB + (bf)*16384 + rr * 128 + c * 16);              \
      }                                                                              \
      _Pragma("unroll") for (int n = 0; n < 2; ++n) {                                \
        int rr = brr + n * 16;                                                       \
        int c = (kk * 4 + kc) ^ (rr & 7);                                            \
        bv[n] = *(const bf16x8*)(BsB + (bf)*8192 + rr * 128 + c * 16);               \
      }                                                                              \
      _Pragma("unroll") for (int m = 0; m < 4; ++m) _Pragma("unroll") for (int n = 0; \
                                                                          n < 2; ++n) \
          acc[m][n] = __builtin_amdgcn_mfma_f32_16x16x32_bf16(av[m], bv[n], acc[m][n], 0, 0, 0); \
    }                                                                                \
  } while (0)

  const int nseg = (MODE == 1) ? 2 : 1;
  for (int seg = 0; seg < nseg; ++seg) {
    const int row = (MODE == 1) ? (seg ? (15 - by) : by) : by;
    const int m0 = row * 128;
    const int KT = (MODE == 1) ? ((m0 + 128) >> 6) : (K >> 6);
    const unsigned short* Ag = A + (long)(m0 + srow) * K + sch * 8;

    f32x4 acc[4][2];
#pragma unroll
    for (int i = 0; i < 4; ++i)
#pragma unroll
      for (int j = 0; j < 2; ++j) acc[i][j] = f32x4{0.f, 0.f, 0.f, 0.f};

    if constexpr (MODE == 1) {
      // depth-2: stages t+1, t+2 in flight; vmcnt(12) retires stage(t).
      STG64(Ag, 0, 0);
      STG64(Ag, 1, 1);  // KT >= 2 always
      for (int kt = 0; kt < KT; ++kt) {
        if (kt + 2 < KT) {
          STG64(Ag, kt + 2, (kt + 2) % 3);
          asm volatile("s_waitcnt vmcnt(12)" ::: "memory");
        } else if (kt + 1 < KT) {
          asm volatile("s_waitcnt vmcnt(6)" ::: "memory");
        } else {
          asm volatile("s_waitcnt vmcnt(0)" ::: "memory");
        }
        __builtin_amdgcn_s_barrier();
        CMP64(kt % 3);
        __builtin_amdgcn_s_barrier();
      }
    } else {
      // depth-1: stage(t+1) in flight; vmcnt(6) retires stage(t).
      STG64(Ag, 0, 0);
      for (int kt = 0; kt < KT; ++kt) {
        if (kt + 1 < KT) {
          STG64(Ag, kt + 1, (kt + 1) & 1);
          asm volatile("s_waitcnt vmcnt(6)" ::: "memory");
        } else {
          asm volatile("s_waitcnt vmcnt(0)" ::: "memory");
        }
        __builtin_amdgcn_s_barrier();
        CMP64(kt & 1);
        __builtin_amdgcn_s_barrier();
      }
    }

    const int rb = m0 + wr + (l >> 4) * 4;
    const int cb = n0 + wc + (l & 15);
#pragma unroll
    for (int m = 0; m < 4; ++m)
#pragma unroll
      for (int n = 0; n < 2; ++n)
#pragma unroll
        for (int i = 0; i < 4; ++i) {
          float v = acc[m][n][i] * alpha;
          long off = (long)(rb + m * 16 + i) * N + (cb + n * 16);
          if constexpr (sizeof(CT) == 2)
            C[off] = f2bf(v);
          else
            C[off] = v;
        }
  }
#undef STG64
#undef CMP64
}

// ---------------- causal row softmax, live-region only ----------------------
__global__ __launch_bounds__(256) void k_softmax(unsigned short* __restrict__ P, int S) {
  const int t = threadIdx.x;
  const int wv = t >> 6, l = t & 63;
  const int q = blockIdx.x * 4 + wv;
  unsigned short* row = P + ((long)blockIdx.y * S + q) * S;
  const int nch = (q >> 9) + 1;

  uint4 raw[4];
  float v[32];
#pragma unroll
  for (int j = 0; j < 4; ++j)
    if (j < nch) raw[j] = ((const uint4*)row)[j * 64 + l];
#pragma unroll
  for (int j = 0; j < 4; ++j) {
    if (j < nch) {
      unsigned int rw[4] = {raw[j].x, raw[j].y, raw[j].z, raw[j].w};
#pragma unroll
      for (int e = 0; e < 8; ++e)
        v[j * 8 + e] = bf2f((unsigned short)((rw[e >> 1] >> ((e & 1) * 16)) & 0xFFFF));
    }
  }

  float mx = -3.0e38f;
#pragma unroll
  for (int j = 0; j < 4; ++j)
    if (j < nch) {
#pragma unroll
      for (int e = 0; e < 8; ++e) {
        int col = j * 512 + l * 8 + e;
        if (col <= q) mx = fmaxf(mx, v[j * 8 + e]);
      }
    }
#pragma unroll
  for (int o = 32; o >= 1; o >>= 1) mx = fmaxf(mx, __shfl_xor(mx, o, 64));

  float s = 0.f;
#pragma unroll
  for (int j = 0; j < 4; ++j)
    if (j < nch) {
#pragma unroll
      for (int e = 0; e < 8; ++e) {
        int col = j * 512 + l * 8 + e;
        float ev = (col <= q) ? __expf(v[j * 8 + e] - mx) : 0.f;
        v[j * 8 + e] = ev;
        s += ev;
      }
    }
#pragma unroll
  for (int o = 32; o >= 1; o >>= 1) s += __shfl_xor(s, o, 64);
  const float inv = 1.f / s;

#pragma unroll
  for (int j = 0; j < 4; ++j)
    if (j < nch) {
      uint4 ow;
      unsigned int o2[4];
#pragma unroll
      for (int jj = 0; jj < 4; ++jj)
        o2[jj] = (unsigned)f2bf(v[j * 8 + 2 * jj] * inv) |
                 ((unsigned)f2bf(v[j * 8 + 2 * jj + 1] * inv) << 16);
      ow.x = o2[0]; ow.y = o2[1]; ow.z = o2[2]; ow.w = o2[3];
      ((uint4*)row)[j * 64 + l] = ow;
    }
}

// ---------------------------------------------------------------------------
extern "C" void kernel_launch(void* const* d_in, const int* in_sizes, int n_in, void* d_out,
                              int out_size, void* d_ws, size_t ws_size, hipStream_t stream) {
  const int B = 4, S = 2048, D = 1024;
  const long MS = (long)B * S;

  const float* x = (const float*)d_in[0];
  const float* Wq = (const float*)d_in[1];
  const float* Wk = (const float*)d_in[2];
  const float* Wv = (const float*)d_in[3];
  float* out = (float*)d_out;

  unsigned short* xb = (unsigned short*)d_ws;   // [8192][1024]
  unsigned short* Wt = xb + MS * D;             // 3 x [1024][1024] (transposed)
  unsigned short* Qb = Wt + 3L * D * D;         // [8192][1024]
  unsigned short* Kb = Qb + MS * D;             // [8192][1024]
  unsigned short* Vt = Kb + MS * D;             // 4 x [1024][2048]
  unsigned short* P  = Vt + MS * D;             // 4 x [2048][2048]
  (void)ws_size;

  long n = MS * D;
  const int ncvt = (int)(n / 8 / 256);
  const int ntrw = 3 * (D / 32) * (D / 32);
  k_prep<<<ncvt + ntrw, 256, 0, stream>>>(x, xb, Wq, Wk, Wv, Wt, n, ncvt, D);
  // Q,K projections (8-phase 256^2): nwg = 4*32*2 = 256
  k_gemm256<unsigned short><<<256, 512, 0, stream>>>(
      xb, Wt, Qb, /*nx=*/D / 256, /*ny=*/(int)(MS / 256), /*N=*/D, /*K=*/D,
      /*sA=*/0L, /*sB=*/(long)D * D, /*sC=*/MS * D, 1.0f);
  // V^T direct (2-phase dbuf): nwg = 16*8*4 = 512
  k_gemm_bt<unsigned short><<<512, 256, 0, stream>>>(
      Wt + 2L * D * D, xb, Vt, /*nx=*/S / 128, /*ny=*/D / 128, /*N=*/S, /*K=*/D,
      /*sA=*/0L, /*sB=*/(long)S * D, /*sC=*/(long)D * S, 1.0f);
  // scores: 64-col triangular, 1088 uniform blocks, 2-buffer vmcnt(6)
  k_gemm_bt64<unsigned short, 0><<<1088, 256, 0, stream>>>(
      Qb, Kb, P, /*N=*/S, /*K=*/D,
      /*sA=*/(long)S * D, /*sB=*/(long)S * D, /*sC=*/(long)S * S, 0.03125f);
  // causal softmax (live region only)
  k_softmax<<<dim3(S / 4, B), 256, 0, stream>>>(P, S);
  // PV: fused row-pairs, depth-2 pipeline (nwg = 4*8*16 = 512)
  k_gemm_bt64<float, 1><<<512, 256, 0, stream>>>(
      P, Vt, out, /*N=*/D, /*K=*/S,
      /*sA=*/(long)S * S, /*sB=*/(long)D * S, /*sC=*/(long)S * D, 1.0f);
}

// Round 11
// 139.261 us; speedup vs baseline: 1.0635x; 1.0203x over previous
//
#include <hip/hip_runtime.h>

// ---------------------------------------------------------------------------
// CausalAttention: out = softmax(mask(QK^T/sqrt(D))) @ V,  Q/K/V = x @ W_{q,k,v}
// B=4, S=2048, D_IN=D_OUT=1024, fp32 in/out, bf16 MFMA internally.
// R11: revert to R8 config (best measured, 139.2us). R9 (scores on 128^2
// dbuf: occupancy 2/CU vs 2.125 demand -> +9us) and R10 (scores 48KB dbuf:
// 6->3 blocks/CU TLP loss -> +3us) both regressed; scores' optimum is the
// high-occupancy single-buffered 128x64 triangular config. All dispatches
// now sit within ~5-15% of their documented structure ceilings.
// ---------------------------------------------------------------------------

typedef __bf16 bf16x8 __attribute__((ext_vector_type(8)));
typedef float f32x4 __attribute__((ext_vector_type(4)));

__device__ __forceinline__ unsigned short f2bf(float f) {
  unsigned int u = __builtin_bit_cast(unsigned int, f);
  u += 0x7FFFu + ((u >> 16) & 1u);  // RNE
  return (unsigned short)(u >> 16);
}
__device__ __forceinline__ float bf2f(unsigned short h) {
  unsigned int u = ((unsigned int)h) << 16;
  return __builtin_bit_cast(float, u);
}

#define GLDS16(g, l)                                                                   \
  __builtin_amdgcn_global_load_lds((const __attribute__((address_space(1))) void*)(g), \
                                   (__attribute__((address_space(3))) void*)(l), 16, 0, 0)

// ---------------- merged: fp32->bf16 convert + W transpose ------------------
__global__ __launch_bounds__(256) void k_prep(const float* __restrict__ x,
                                              unsigned short* __restrict__ xb,
                                              const float* __restrict__ W0,
                                              const float* __restrict__ W1,
                                              const float* __restrict__ W2,
                                              unsigned short* __restrict__ Wt, long n, int ncvt,
                                              int D) {
  const int b = blockIdx.x;
  const int t = threadIdx.x;
  if (b < ncvt) {
    long i = ((long)b * 256 + t) * 8;
    if (i >= n) return;
    float4 a = *(const float4*)(x + i);
    float4 c = *(const float4*)(x + i + 4);
    uint4 o;
    o.x = (unsigned)f2bf(a.x) | ((unsigned)f2bf(a.y) << 16);
    o.y = (unsigned)f2bf(a.z) | ((unsigned)f2bf(a.w) << 16);
    o.z = (unsigned)f2bf(c.x) | ((unsigned)f2bf(c.y) << 16);
    o.w = (unsigned)f2bf(c.z) | ((unsigned)f2bf(c.w) << 16);
    *(uint4*)(xb + i) = o;
    return;
  }
  const int id = b - ncvt;
  const int nt = (D / 32) * (D / 32);
  const int z = id / nt;
  const int rem = id - z * nt;
  const int by = (rem >> 5) * 32, bx = (rem & 31) * 32;
  const float* W = z == 0 ? W0 : (z == 1 ? W1 : W2);
  unsigned short* out = Wt + (long)z * D * D;
  __shared__ float tile[32][33];
  const int tx = t & 31, ty = t >> 5;
#pragma unroll
  for (int j = 0; j < 4; ++j) tile[ty + j * 8][tx] = W[(long)(by + ty + j * 8) * D + bx + tx];
  __syncthreads();
#pragma unroll
  for (int j = 0; j < 4; ++j)
    out[(long)(bx + ty + j * 8) * D + by + tx] = f2bf(tile[tx][ty + j * 8]);
}

// ======================= 256^2 8-phase BT GEMM (projections) ================
template <typename CT>
__global__ __launch_bounds__(512, 2) void k_gemm256(const unsigned short* __restrict__ A,
                                                    const unsigned short* __restrict__ B,
                                                    CT* __restrict__ C, int nx, int ny, int N,
                                                    int K, long sA, long sB, long sC,
                                                    float alpha) {
  const unsigned bid = blockIdx.x;
  const unsigned cpx = gridDim.x >> 3;
  const unsigned logical = (bid & 7) * cpx + (bid >> 3);
  const int per_z = nx * ny;
  const int z = (int)(logical / per_z);
  const int rem = (int)(logical - (unsigned)z * per_z);
  const int by = rem / nx;
  const int bx = rem - by * nx;
  const int m0 = by * 256, n0 = bx * 256;
  A += (long)z * sA;
  B += (long)z * sB;
  C += (long)z * sC;

  __shared__ char lds[131072];

  const int t = threadIdx.x;
  const int l = t & 63;
  const int w = t >> 6;
  const int wm = w >> 2;
  const int wn = w & 3;

  const int srow = t >> 3;
  const int sch = (t & 7) ^ (srow & 7);
  const int soff = t * 16;

#define STG(mat, bf, hf, kt)                                                              \
  do {                                                                                    \
    const unsigned short* g =                                                             \
        ((mat) ? B + (long)(n0 + (hf)*128 + srow) * K : A + (long)(m0 + (hf)*128 + srow) * K) + \
        (long)(kt)*64 + sch * 8;                                                          \
    char* d = lds + (mat)*65536 + (bf)*32768 + (hf)*16384 + soff;                         \
    GLDS16(g, d);                                                                         \
    GLDS16(g + (long)64 * K, d + 8192);                                                   \
  } while (0)

  const int lx = l & 15;
  const int kx0 = ((l >> 4) ^ (l & 7)) * 16;
  const int kx1 = ((4 + (l >> 4)) ^ (l & 7)) * 16;
  char* const aB = lds + wm * 16384 + lx * 128;
  char* const bB = lds + 65536 + (wn >> 1) * 16384 + ((wn & 1) * 64 + lx) * 128;

  bf16x8 av[4][2], bv0[2][2], bv1[2][2];
  f32x4 acc[8][4];
#pragma unroll
  for (int i = 0; i < 8; ++i)
#pragma unroll
    for (int jn = 0; jn < 4; ++jn) acc[i][jn] = f32x4{0.f, 0.f, 0.f, 0.f};

#define RDA(bf, mh)                                                     \
  do {                                                                  \
    _Pragma("unroll") for (int m4 = 0; m4 < 4; ++m4) {                  \
      char* p = aB + (bf)*32768 + ((mh)*64 + m4 * 16) * 128;            \
      av[m4][0] = *(const bf16x8*)(p + kx0);                            \
      av[m4][1] = *(const bf16x8*)(p + kx1);                            \
    }                                                                   \
  } while (0)
#define RDB(dst, bf, nh)                                                \
  do {                                                                  \
    _Pragma("unroll") for (int n2 = 0; n2 < 2; ++n2) {                  \
      char* p = bB + (bf)*32768 + (((nh)*2 + n2) * 16) * 128;           \
      dst[n2][0] = *(const bf16x8*)(p + kx0);                           \
      dst[n2][1] = *(const bf16x8*)(p + kx1);                           \
    }                                                                   \
  } while (0)
#define MFM(bv, mh, nh)                                                                    \
  do {                                                                                     \
    __builtin_amdgcn_s_setprio(1);                                                         \
    _Pragma("unroll") for (int m4 = 0; m4 < 4; ++m4) _Pragma("unroll") for (int n2 = 0;    \
                                                                            n2 < 2; ++n2) { \
      acc[(mh)*4 + m4][(nh)*2 + n2] = __builtin_amdgcn_mfma_f32_16x16x32_bf16(             \
          av[m4][0], bv[n2][0], acc[(mh)*4 + m4][(nh)*2 + n2], 0, 0, 0);                   \
      acc[(mh)*4 + m4][(nh)*2 + n2] = __builtin_amdgcn_mfma_f32_16x16x32_bf16(             \
          av[m4][1], bv[n2][1], acc[(mh)*4 + m4][(nh)*2 + n2], 0, 0, 0);                   \
    }                                                                                      \
    __builtin_amdgcn_s_setprio(0);                                                         \
  } while (0)
#define BAR __builtin_amdgcn_s_barrier()
#define VMC(n) asm volatile("s_waitcnt vmcnt(" #n ")" ::: "memory")

  const int KT = K >> 6;
  const int NIT = KT >> 1;

  STG(0, 0, 0, 0); STG(0, 0, 1, 0); STG(1, 0, 0, 0); STG(1, 0, 1, 0);
  STG(1, 1, 0, 1); STG(1, 1, 1, 1); STG(0, 1, 0, 1);
  VMC(6);
  BAR;

  for (int j = 0; j < NIT; ++j) {
    const bool full = (j < NIT - 1);
    RDA(0, 0); RDB(bv0, 0, 0);
    STG(0, 1, 1, 2 * j + 1);
    BAR; MFM(bv0, 0, 0); BAR;
    RDB(bv1, 0, 1);
    BAR; MFM(bv1, 0, 1); BAR;
    RDA(0, 1);
    if (full) STG(1, 0, 0, 2 * j + 2);
    BAR; MFM(bv1, 1, 1); BAR;
    if (full) {
      STG(0, 0, 0, 2 * j + 2); STG(1, 0, 1, 2 * j + 2);
      VMC(6);
    } else {
      VMC(0);
    }
    BAR; MFM(bv0, 1, 0); BAR;
    RDA(1, 0); RDB(bv0, 1, 0);
    if (full) STG(0, 0, 1, 2 * j + 2);
    BAR; MFM(bv0, 0, 0); BAR;
    RDB(bv1, 1, 1);
    BAR; MFM(bv1, 0, 1); BAR;
    RDA(1, 1);
    if (full) STG(1, 1, 0, 2 * j + 3);
    BAR; MFM(bv1, 1, 1); BAR;
    if (full) {
      STG(1, 1, 1, 2 * j + 3); STG(0, 1, 0, 2 * j + 3);
      VMC(6);
    }
    BAR; MFM(bv0, 1, 0); BAR;
  }

  const int rb = m0 + wm * 128 + (l >> 4) * 4;
  const int cb = n0 + wn * 64 + (l & 15);
#pragma unroll
  for (int m = 0; m < 8; ++m)
#pragma unroll
    for (int n = 0; n < 4; ++n)
#pragma unroll
      for (int i = 0; i < 4; ++i) {
        float v = acc[m][n][i] * alpha;
        long off = (long)(rb + m * 16 + i) * N + (cb + n * 16);
        if constexpr (sizeof(CT) == 2)
          C[off] = f2bf(v);
        else
          C[off] = v;
      }
#undef STG
#undef RDA
#undef RDB
#undef MFM
#undef BAR
#undef VMC
}

// ============== 128^2 BT GEMM, 2-phase dbuf + vmcnt(8) (V^T) ================
template <typename CT>
__global__ __launch_bounds__(256) void k_gemm_bt(const unsigned short* __restrict__ A,
                                                 const unsigned short* __restrict__ B,
                                                 CT* __restrict__ C, int nx, int ny, int N, int K,
                                                 long sA, long sB, long sC, float alpha) {
  const unsigned bid = blockIdx.x;
  const unsigned cpx = gridDim.x >> 3;
  const unsigned logical = (bid & 7) * cpx + (bid >> 3);
  const int per_z = nx * ny;
  const int z = (int)(logical / per_z);
  const int r = (int)(logical - (unsigned)z * per_z);
  const int by = r / nx;
  const int bx = r - by * nx;
  const int m0 = by * 128;
  const int n0 = bx * 128;
  A += (long)z * sA;
  B += (long)z * sB;
  C += (long)z * sC;

  __shared__ unsigned short As[2 * 128 * 64];
  __shared__ unsigned short Bs[2 * 128 * 64];
  char* const AsB = (char*)As;
  char* const BsB = (char*)Bs;

  const int t = threadIdx.x;
  const int l = t & 63;
  const int w = t >> 6;
  const int wr = (w >> 1) * 64;
  const int wc = (w & 1) * 64;

  const int srow = t >> 3;
  const int sch = (t & 7) ^ (srow & 7);
  const unsigned short* Ag = A + (long)(m0 + srow) * K + sch * 8;
  const unsigned short* Bg = B + (long)(n0 + srow) * K + sch * 8;
  const int soff = t * 16;

  const int ar = wr + (l & 15);
  const int brr = wc + (l & 15);
  const int kc = l >> 4;

  f32x4 acc[4][4];
#pragma unroll
  for (int i = 0; i < 4; ++i)
#pragma unroll
    for (int j = 0; j < 4; ++j) acc[i][j] = f32x4{0.f, 0.f, 0.f, 0.f};

#define STGBT(kt, bf)                                                                     \
  do {                                                                                    \
    const long ko = (long)(kt)*64;                                                        \
    _Pragma("unroll") for (int i = 0; i < 4; ++i)                                         \
        GLDS16(Ag + (long)i * 32 * K + ko, AsB + (bf)*16384 + i * 4096 + soff);           \
    _Pragma("unroll") for (int i = 0; i < 4; ++i)                                         \
        GLDS16(Bg + (long)i * 32 * K + ko, BsB + (bf)*16384 + i * 4096 + soff);           \
  } while (0)

  const int KT = K >> 6;
  STGBT(0, 0);
  for (int kt = 0; kt < KT; ++kt) {
    if (kt + 1 < KT) {
      STGBT(kt + 1, (kt + 1) & 1);
      asm volatile("s_waitcnt vmcnt(8)" ::: "memory");
    } else {
      asm volatile("s_waitcnt vmcnt(0)" ::: "memory");
    }
    __builtin_amdgcn_s_barrier();
    const int bf = kt & 1;
#pragma unroll
    for (int kk = 0; kk < 2; ++kk) {
      bf16x8 av[4], bv[4];
#pragma unroll
      for (int m = 0; m < 4; ++m) {
        int rr = ar + m * 16;
        int c = (kk * 4 + kc) ^ (rr & 7);
        av[m] = *(const bf16x8*)(AsB + bf * 16384 + rr * 128 + c * 16);
      }
#pragma unroll
      for (int n = 0; n < 4; ++n) {
        int rr = brr + n * 16;
        int c = (kk * 4 + kc) ^ (rr & 7);
        bv[n] = *(const bf16x8*)(BsB + bf * 16384 + rr * 128 + c * 16);
      }
#pragma unroll
      for (int m = 0; m < 4; ++m)
#pragma unroll
        for (int n = 0; n < 4; ++n)
          acc[m][n] = __builtin_amdgcn_mfma_f32_16x16x32_bf16(av[m], bv[n], acc[m][n], 0, 0, 0);
    }
    __builtin_amdgcn_s_barrier();
  }
#undef STGBT

  const int rb = m0 + wr + (l >> 4) * 4;
  const int cb = n0 + wc + (l & 15);
#pragma unroll
  for (int m = 0; m < 4; ++m)
#pragma unroll
    for (int n = 0; n < 4; ++n)
#pragma unroll
      for (int i = 0; i < 4; ++i) {
        float v = acc[m][n][i] * alpha;
        long off = (long)(rb + m * 16 + i) * N + (cb + n * 16);
        if constexpr (sizeof(CT) == 2)
          C[off] = f2bf(v);
        else
          C[off] = v;
      }
}

// ======================= 128x64 BT GEMM, uniform-work modes =================
// MODE 0 (scores): 64-col triangular decode, 1088 uniform blocks, single-
//   buffered 24 KiB (high occupancy TLP regime — R9/R10 proved dbuf regresses).
// MODE 1 (PV): fused row-pair (by, 15-by), 34 K-tiles/block uniform; 3-buffer
//   depth-2 pipeline, vmcnt(12)/(6)/(0); K clamped at causal diagonal.
template <typename CT, int MODE>
__global__ __launch_bounds__(256) void k_gemm_bt64(const unsigned short* __restrict__ A,
                                                   const unsigned short* __restrict__ B,
                                                   CT* __restrict__ C, int N, int K, long sA,
                                                   long sB, long sC, float alpha) {
  const unsigned bid = blockIdx.x;
  const unsigned cpx = gridDim.x >> 3;
  const unsigned logical = (bid & 7) * cpx + (bid >> 3);
  int z, by, bx;
  if constexpr (MODE == 0) {
    const int per_z = 272;
    z = (int)(logical / per_z);
    int r = (int)(logical - (unsigned)z * per_z);
    int b = (int)((sqrtf(4.f * (float)r + 1.f) - 1.f) * 0.5f);
    while ((b + 1) * (b + 2) <= r) ++b;
    while (b * (b + 1) > r) --b;
    by = b;
    bx = r - b * (b + 1);
  } else {
    const int nx = N >> 6;
    const int per_z = 8 * nx;
    z = (int)(logical / per_z);
    int r = (int)(logical - (unsigned)z * per_z);
    by = r / nx;
    bx = r - by * nx;
  }
  A += (long)z * sA;
  B += (long)z * sB;
  C += (long)z * sC;

  __shared__ unsigned short As[(MODE == 1 ? 3 : 1) * 128 * 64];
  __shared__ unsigned short Bs[(MODE == 1 ? 3 : 1) * 64 * 64];
  char* const AsB = (char*)As;
  char* const BsB = (char*)Bs;

  const int t = threadIdx.x;
  const int l = t & 63;
  const int w = t >> 6;
  const int wr = (w >> 1) * 64;
  const int wc = (w & 1) * 32;

  const int srow = t >> 3;
  const int sch = (t & 7) ^ (srow & 7);
  const int soff = t * 16;

  const int ar = wr + (l & 15);
  const int brr = wc + (l & 15);
  const int kc = l >> 4;

  const int n0 = bx * 64;
  const unsigned short* Bg = B + (long)(n0 + srow) * K + sch * 8;

#define STG64(Agp, kt, bf)                                                           \
  do {                                                                               \
    const long ko = (long)(kt)*64;                                                   \
    _Pragma("unroll") for (int i = 0; i < 4; ++i)                                    \
        GLDS16((Agp) + (long)i * 32 * K + ko, AsB + (bf)*16384 + i * 4096 + soff);   \
    _Pragma("unroll") for (int i = 0; i < 2; ++i)                                    \
        GLDS16(Bg + (long)i * 32 * K + ko, BsB + (bf)*8192 + i * 4096 + soff);       \
  } while (0)

#define CMP64(bf)                                                                    \
  do {                                                                               \
    _Pragma("unroll") for (int kk = 0; kk < 2; ++kk) {                               \
      bf16x8 av[4], bv[2];                                                           \
      _Pragma("unroll") for (int m = 0; m < 4; ++m) {                                \
        int rr = ar + m * 16;                                                        \
        int c = (kk * 4 + kc) ^ (rr & 7);                                            \
        av[m] = *(const bf16x8*)(AsB + (bf)*16384 + rr * 128 + c * 16);              \
      }                                                                              \
      _Pragma("unroll") for (int n = 0; n < 2; ++n) {                                \
        int rr = brr + n * 16;                                                       \
        int c = (kk * 4 + kc) ^ (rr & 7);                                            \
        bv[n] = *(const bf16x8*)(BsB + (bf)*8192 + rr * 128 + c * 16);               \
      }                                                                              \
      _Pragma("unroll") for (int m = 0; m < 4; ++m) _Pragma("unroll") for (int n = 0; \
                                                                          n < 2; ++n) \
          acc[m][n] = __builtin_amdgcn_mfma_f32_16x16x32_bf16(av[m], bv[n], acc[m][n], 0, 0, 0); \
    }                                                                                \
  } while (0)

  const int nseg = (MODE == 1) ? 2 : 1;
  for (int seg = 0; seg < nseg; ++seg) {
    const int row = (MODE == 1) ? (seg ? (15 - by) : by) : by;
    const int m0 = row * 128;
    const int KT = (MODE == 1) ? ((m0 + 128) >> 6) : (K >> 6);
    const unsigned short* Ag = A + (long)(m0 + srow) * K + sch * 8;

    f32x4 acc[4][2];
#pragma unroll
    for (int i = 0; i < 4; ++i)
#pragma unroll
      for (int j = 0; j < 2; ++j) acc[i][j] = f32x4{0.f, 0.f, 0.f, 0.f};

    if constexpr (MODE == 1) {
      // depth-2: stages t+1, t+2 in flight; vmcnt(12) retires stage(t).
      STG64(Ag, 0, 0);
      STG64(Ag, 1, 1);  // KT >= 2 always
      for (int kt = 0; kt < KT; ++kt) {
        if (kt + 2 < KT) {
          STG64(Ag, kt + 2, (kt + 2) % 3);
          asm volatile("s_waitcnt vmcnt(12)" ::: "memory");
        } else if (kt + 1 < KT) {
          asm volatile("s_waitcnt vmcnt(6)" ::: "memory");
        } else {
          asm volatile("s_waitcnt vmcnt(0)" ::: "memory");
        }
        __builtin_amdgcn_s_barrier();
        CMP64(kt % 3);
        __builtin_amdgcn_s_barrier();
      }
    } else {
      for (int kt = 0; kt < KT; ++kt) {
        STG64(Ag, kt, 0);
        __syncthreads();
        CMP64(0);
        __syncthreads();
      }
    }

    const int rb = m0 + wr + (l >> 4) * 4;
    const int cb = n0 + wc + (l & 15);
#pragma unroll
    for (int m = 0; m < 4; ++m)
#pragma unroll
      for (int n = 0; n < 2; ++n)
#pragma unroll
        for (int i = 0; i < 4; ++i) {
          float v = acc[m][n][i] * alpha;
          long off = (long)(rb + m * 16 + i) * N + (cb + n * 16);
          if constexpr (sizeof(CT) == 2)
            C[off] = f2bf(v);
          else
            C[off] = v;
        }
  }
#undef STG64
#undef CMP64
}

// ---------------- causal row softmax, live-region only ----------------------
__global__ __launch_bounds__(256) void k_softmax(unsigned short* __restrict__ P, int S) {
  const int t = threadIdx.x;
  const int wv = t >> 6, l = t & 63;
  const int q = blockIdx.x * 4 + wv;
  unsigned short* row = P + ((long)blockIdx.y * S + q) * S;
  const int nch = (q >> 9) + 1;

  uint4 raw[4];
  float v[32];
#pragma unroll
  for (int j = 0; j < 4; ++j)
    if (j < nch) raw[j] = ((const uint4*)row)[j * 64 + l];
#pragma unroll
  for (int j = 0; j < 4; ++j) {
    if (j < nch) {
      unsigned int rw[4] = {raw[j].x, raw[j].y, raw[j].z, raw[j].w};
#pragma unroll
      for (int e = 0; e < 8; ++e)
        v[j * 8 + e] = bf2f((unsigned short)((rw[e >> 1] >> ((e & 1) * 16)) & 0xFFFF));
    }
  }

  float mx = -3.0e38f;
#pragma unroll
  for (int j = 0; j < 4; ++j)
    if (j < nch) {
#pragma unroll
      for (int e = 0; e < 8; ++e) {
        int col = j * 512 + l * 8 + e;
        if (col <= q) mx = fmaxf(mx, v[j * 8 + e]);
      }
    }
#pragma unroll
  for (int o = 32; o >= 1; o >>= 1) mx = fmaxf(mx, __shfl_xor(mx, o, 64));

  float s = 0.f;
#pragma unroll
  for (int j = 0; j < 4; ++j)
    if (j < nch) {
#pragma unroll
      for (int e = 0; e < 8; ++e) {
        int col = j * 512 + l * 8 + e;
        float ev = (col <= q) ? __expf(v[j * 8 + e] - mx) : 0.f;
        v[j * 8 + e] = ev;
        s += ev;
      }
    }
#pragma unroll
  for (int o = 32; o >= 1; o >>= 1) s += __shfl_xor(s, o, 64);
  const float inv = 1.f / s;

#pragma unroll
  for (int j = 0; j < 4; ++j)
    if (j < nch) {
      uint4 ow;
      unsigned int o2[4];
#pragma unroll
      for (int jj = 0; jj < 4; ++jj)
        o2[jj] = (unsigned)f2bf(v[j * 8 + 2 * jj] * inv) |
                 ((unsigned)f2bf(v[j * 8 + 2 * jj + 1] * inv) << 16);
      ow.x = o2[0]; ow.y = o2[1]; ow.z = o2[2]; ow.w = o2[3];
      ((uint4*)row)[j * 64 + l] = ow;
    }
}

// ---------------------------------------------------------------------------
extern "C" void kernel_launch(void* const* d_in, const int* in_sizes, int n_in, void* d_out,
                              int out_size, void* d_ws, size_t ws_size, hipStream_t stream) {
  const int B = 4, S = 2048, D = 1024;
  const long MS = (long)B * S;

  const float* x = (const float*)d_in[0];
  const float* Wq = (const float*)d_in[1];
  const float* Wk = (const float*)d_in[2];
  const float* Wv = (const float*)d_in[3];
  float* out = (float*)d_out;

  unsigned short* xb = (unsigned short*)d_ws;   // [8192][1024]
  unsigned short* Wt = xb + MS * D;             // 3 x [1024][1024] (transposed)
  unsigned short* Qb = Wt + 3L * D * D;         // [8192][1024]
  unsigned short* Kb = Qb + MS * D;             // [8192][1024]
  unsigned short* Vt = Kb + MS * D;             // 4 x [1024][2048]
  unsigned short* P  = Vt + MS * D;             // 4 x [2048][2048]
  (void)ws_size;

  long n = MS * D;
  const int ncvt = (int)(n / 8 / 256);
  const int ntrw = 3 * (D / 32) * (D / 32);
  k_prep<<<ncvt + ntrw, 256, 0, stream>>>(x, xb, Wq, Wk, Wv, Wt, n, ncvt, D);
  // Q,K projections (8-phase 256^2): nwg = 4*32*2 = 256
  k_gemm256<unsigned short><<<256, 512, 0, stream>>>(
      xb, Wt, Qb, /*nx=*/D / 256, /*ny=*/(int)(MS / 256), /*N=*/D, /*K=*/D,
      /*sA=*/0L, /*sB=*/(long)D * D, /*sC=*/MS * D, 1.0f);
  // V^T direct (2-phase dbuf): nwg = 16*8*4 = 512
  k_gemm_bt<unsigned short><<<512, 256, 0, stream>>>(
      Wt + 2L * D * D, xb, Vt, /*nx=*/S / 128, /*ny=*/D / 128, /*N=*/S, /*K=*/D,
      /*sA=*/0L, /*sB=*/(long)S * D, /*sC=*/(long)D * S, 1.0f);
  // scores: 64-col triangular, 1088 uniform blocks, single-buffered
  k_gemm_bt64<unsigned short, 0><<<1088, 256, 0, stream>>>(
      Qb, Kb, P, /*N=*/S, /*K=*/D,
      /*sA=*/(long)S * D, /*sB=*/(long)S * D, /*sC=*/(long)S * S, 0.03125f);
  // causal softmax (live region only)
  k_softmax<<<dim3(S / 4, B), 256, 0, stream>>>(P, S);
  // PV: fused row-pairs, depth-2 pipeline (nwg = 4*8*16 = 512)
  k_gemm_bt64<float, 1><<<512, 256, 0, stream>>>(
      P, Vt, out, /*N=*/D, /*K=*/S,
      /*sA=*/(long)S * S, /*sB=*/(long)D * S, /*sC=*/(long)S * D, 1.0f);
}